// Round 8
// baseline (124.891 us; speedup 1.0000x reference)
//
#include <hip/hip_runtime.h>
#include <stdint.h>

#define NN 1536
#define EE 49152
#define EMB 32
#define HEADS 3
#define SLOPE 0.2f
#define CAP 72             // per-row total capacity; degree ~ Poisson(32), measured max ~60
#define REP 4              // counter/bucket replication
#define CAP2 28            // per-replica capacity; per-replica degree ~ Poisson(8), P(>28) ~ 1e-9
#define SES 67             // sE row stride (67 mod 32 = 3, coprime -> conflict-free strided reads)
#define EBLK (EE/256)      // 192 edge blocks
#define NBLK (NN/8)        // 192 node blocks
#define MAGIC 0x137FBEEF   // counters-ready flag value (workspace poison is a repeated fill pattern != this)

__device__ __forceinline__ float lrelu(float x){ return x >= 0.f ? x : SLOPE*x; }

// ---- runtime detection of bool-mask storage (int32 / uint8 / f32) ----
__device__ int detect_mask_layout(const unsigned char* p){
  const int* pi = (const int*)p;
  bool ok = true;
  for (int k=0;k<64 && ok;k++){ int v = pi[k]; ok = (v==0 || v==1); }
  if (ok) return 0;
  ok = true;
  for (int k=0;k<256 && ok;k++){ ok = (p[k] <= 1); }
  if (ok) return 1;
  return 2;
}
__device__ bool mask_at(const unsigned char* p, int layout, int i){
  if (layout==0) return ((const int*)p)[i] != 0;
  if (layout==1) return p[i] != 0;
  return ((const float*)p)[i] != 0.f;
}

// ---- K1: block 0: zero counters + set ready flag (replaces the memset dispatch).
//          blocks [1, EBLK]: bucket insert gated on the flag (1 thread/edge).
//          blocks (EBLK, EBLK+NBLK]: node embeddings. ----
__global__ __launch_bounds__(256) void k_prep(
    const float* __restrict__ node_f,
    const float* __restrict__ edge_attr, const float* __restrict__ edge_type,
    const float* __restrict__ W_veh, const float* __restrict__ W_ped,
    const float* __restrict__ W_att, const float* __restrict__ W_upd,
    const int* __restrict__ ei, const unsigned char* __restrict__ veh_mask,
    int* __restrict__ cnt, int* flag,
    int* __restrict__ segD, float4* __restrict__ segF,
    float* __restrict__ tar, float* __restrict__ nbr, float* __restrict__ nb)
{
  const int t = threadIdx.x;
  const int b = blockIdx.x;

  if (b == 0){
    // zero counters, then publish readiness (release)
    for (int i=t; i<REP*NN; i+=256) cnt[i] = 0;
    __threadfence();
    __syncthreads();
    if (t == 0) __hip_atomic_store(flag, MAGIC, __ATOMIC_RELEASE, __HIP_MEMORY_SCOPE_AGENT);
    return;
  }

  if (b <= EBLK){
    const int eb = b - 1;
    const int e = eb*256 + t;
    const int j = eb & (REP-1);
    // issue edge loads before the gate (overlap with the ~1us zeroing wait)
    const int s = ei[e], d = ei[EE + e];
    const float2 ea = ((const float2*)edge_attr)[e];
    const float2 et = ((const float2*)edge_type)[e];
    // gate: counters must be zeroed before any atomic
    if (t == 0){
      int spins = 0;
      while (__hip_atomic_load(flag, __ATOMIC_ACQUIRE, __HIP_MEMORY_SCOPE_AGENT) != MAGIC){
        __builtin_amdgcn_s_sleep(1);
        if (++spins > 20000000) break;    // fail loud (wrong answer), never hang
      }
    }
    __syncthreads();
    const int idx = atomicAdd(&cnt[j*NN + s], 1);
    if (idx < CAP2){
      const size_t sb = ((size_t)j*NN + s)*CAP2 + idx;
      segD[sb] = d;
      segF[sb] = make_float4(ea.x, ea.y, et.x, et.y);
    }
    return;
  }

  // -------- node path: 8 nodes/block, 32 threads/node --------
  __shared__ float sWvehT[EMB*33], sWpedT[EMB*33], sWunT[EMB*33];
  __shared__ float sWt[HEADS*EMB], sWn[HEADS*EMB];
  __shared__ float sF[8*EMB], sEmb[8*EMB];
  __shared__ int layout_s;
  const int i0 = (b - EBLK - 1)*8;
  if (t == 0) layout_s = detect_mask_layout(veh_mask);
  for (int idx=t; idx<EMB*EMB; idx+=256){
    const int mm = idx>>5, kk = idx&31;
    sWvehT[mm*33+kk] = W_veh[idx];
    sWpedT[mm*33+kk] = W_ped[idx];
    sWunT[mm*33+kk]  = W_upd[mm*64 + EMB + kk];   // Wu_n = W_upd[:,32:]
  }
  if (t < HEADS*EMB){
    const int h = t>>5, c = t&31;
    sWt[t] = W_att[h*128 + c];        // W_tar
    sWn[t] = W_att[h*128 + 96 + c];   // W_nbr
  }
  sF[t] = node_f[(size_t)i0*EMB + t];
  __syncthreads();

  const int li = t >> 5, m = t & 31;
  const int i = i0 + li;
  const bool veh = mask_at(veh_mask, layout_s, i);
  const float* WT = veh ? sWvehT : sWpedT;
  float a = 0.f;
  #pragma unroll
  for (int k=0;k<EMB;k++) a += sF[li*EMB+k] * WT[m*33+k];
  sEmb[li*EMB+m] = lrelu(a);
  __syncthreads();

  float bb = 0.f;
  #pragma unroll
  for (int k=0;k<EMB;k++) bb += sEmb[li*EMB+k] * sWunT[m*33+k];
  nb[(size_t)i*EMB + m] = bb;
  if (m < 3){
    float v = 0.f;
    #pragma unroll
    for (int k=0;k<EMB;k++) v += sEmb[li*EMB+k] * sWt[m*EMB+k];
    tar[i*4+m] = v;
  } else if (m < 6){
    const int h = m-3;
    float v = 0.f;
    #pragma unroll
    for (int k=0;k<EMB;k++) v += sEmb[li*EMB+k] * sWn[h*EMB+k];
    nbr[i*4+h] = v;
  }
}

// ---- K2: one block per src row; concatenates the 4 replica sub-buckets.
//          25.6 KB LDS -> 6 blocks/CU -> all 1536 rows resident, one pass. ----
__global__ __launch_bounds__(256, 6) void k_rows(
    const int* __restrict__ cnt, const int* __restrict__ segD,
    const float4* __restrict__ segF,
    const float* __restrict__ W_ea, const float* __restrict__ W_et,
    const float* __restrict__ W_att, const float* __restrict__ W_upd,
    const float* __restrict__ tar, const float* __restrict__ nbr,
    const float* __restrict__ nb, float* __restrict__ out)
{
  const int r = blockIdx.x;
  const int t = threadIdx.x;

  __shared__ int   ld[CAP], canon[CAP], slotidx[CAP], slotof[CAP], cdst[CAP];
  __shared__ float4 pay[CAP];
  __shared__ float sE[CAP*SES];          // per-slot [emb_ea(32) | pad | emb_et(32) | pad2]
  __shared__ float sWea[64], sWet[64], sWedge[HEADS*64];
  __shared__ float pp[HEADS*CAP];
  __shared__ float partial[4*96];
  __shared__ float hden[HEADS];
  __shared__ int np_s, hasdup_s;

  if (t < 64){ sWea[t] = W_ea[t]; sWet[t] = W_et[t]; }
  if (t < HEADS*64) sWedge[t] = W_att[(t>>6)*128 + EMB + (t&63)];   // W_edge
  if (t == 0){ np_s = 0; hasdup_s = 0; }

  // replica counts (uniform scalar loads)
  const int k0 = min(cnt[0*NN + r], CAP2);
  const int k1 = min(cnt[1*NN + r], CAP2);
  const int k2 = min(cnt[2*NN + r], CAP2);
  const int k3 = min(cnt[3*NN + r], CAP2);
  const int o1 = k0, o2 = k0+k1, o3 = k0+k1+k2;
  const int K = min(o3 + k3, CAP);

  if (K == 0){
    // all scores -10000 -> uniform attention over all nodes (lazy fallback; ~never taken)
    float* fb = pp;
    if (t < EMB) fb[t] = 0.f;
    __syncthreads();
    for (int idx=t; idx<NN*EMB; idx+=256) atomicAdd(&fb[idx&31], lrelu(nb[idx]));
    __syncthreads();
    if (t < 96) out[(size_t)r*96 + t] = fb[t&31] * (1.0f/NN);
    return;
  }

  for (int i=t; i<K; i+=256){
    int j, ii;
    if (i < o1){ j = 0; ii = i; }
    else if (i < o2){ j = 1; ii = i - o1; }
    else if (i < o3){ j = 2; ii = i - o2; }
    else { j = 3; ii = i - o3; }
    const size_t sb = ((size_t)j*NN + r)*CAP2 + ii;
    const int d = segD[sb];
    ld[i]  = d;
    cdst[i] = d;                // speculative (valid if no dups)
    pay[i] = segF[sb];
    canon[i] = i;
  }
  __syncthreads();                                      // barrier 1

  // dedup sweep: atomicMin canon + dup flag in one pass
  for (int p=t; p<K*K; p+=256){
    const int i = p / K, j = p - i*K;
    if (j < i && ld[i] == ld[j]){ atomicMin(&canon[i], j); hasdup_s = 1; }
  }
  __syncthreads();                                      // barrier 2

  const bool dup = (hasdup_s != 0);                     // block-uniform
  int Kc = K;
  if (dup){
    // rare path (~28% of rows): compact slots + merge payload sums
    for (int i=t; i<K; i+=256){
      if (canon[i] == i){
        const int s2 = atomicAdd(&np_s, 1);
        slotidx[i] = s2;
        cdst[s2]   = ld[i];
      }
    }
    __syncthreads();
    Kc = np_s;
    for (int i=t; i<K; i+=256) slotof[i] = slotidx[canon[i]];
    for (int idx=t; idx<Kc*SES; idx+=256) sE[idx] = 0.f;
    __syncthreads();
  }

  // per-entry 64-dim edge embedding -> per-slot (sum); linear downstream so summing embs == summing eau/se
  for (int idx=t; idx<K*EMB; idx+=256){
    const int q = idx>>5, m = idx&31;
    const float4 p4 = pay[q];
    const float ea_ = lrelu(p4.x*sWea[2*m] + p4.y*sWea[2*m+1]);
    const float et_ = lrelu(p4.z*sWet[2*m] + p4.w*sWet[2*m+1]);
    if (!dup){
      sE[q*SES + m]      = ea_;
      sE[q*SES + 33 + m] = et_;
    } else {
      const int sl = slotof[q];
      atomicAdd(&sE[sl*SES + m],      ea_);
      atomicAdd(&sE[sl*SES + 33 + m], et_);
    }
  }
  __syncthreads();                                      // barrier 3

  // softmax: head h = wave h; lane q; shfl reductions
  if (t < 192){
    const int h = t >> 6, lane = t & 63;
    const float th = tar[r*4+h];
    float mx = -1e30f;
    for (int q0=0; q0<Kc; q0+=64){
      const int q = q0 + lane;
      if (q < Kc){
        float sev = 0.f;
        #pragma unroll
        for (int k=0;k<EMB;k++)
          sev += sWedge[h*64+k]*sE[q*SES+k] + sWedge[h*64+EMB+k]*sE[q*SES+33+k];
        const float s = lrelu(th + sev + nbr[cdst[q]*4+h]);
        pp[h*CAP+q] = s;
        mx = fmaxf(mx, s);
      }
    }
    #pragma unroll
    for (int d=32; d; d>>=1) mx = fmaxf(mx, __shfl_xor(mx, d, 64));
    float den = 0.f;
    for (int q0=0; q0<Kc; q0+=64){
      const int q = q0 + lane;
      if (q < Kc){
        const float p = __expf(pp[h*CAP+q] - mx);
        pp[h*CAP+q] = p;
        den += p;
      }
    }
    #pragma unroll
    for (int d=32; d; d>>=1) den += __shfl_xor(den, d, 64);
    if (lane == 0) hden[h] = den;
  }
  __syncthreads();                                      // barrier 4

  // output: 8 q-groups x 32 o-lanes; Wu_e row o streamed from global into regs (phase-local)
  {
    const int g = t >> 5, o = t & 31;
    const float4* wrow = (const float4*)(W_upd + (size_t)o*64);  // Wu_e row o = W_upd[o*64 + 0..31]
    const float4 w0=wrow[0], w1=wrow[1], w2=wrow[2], w3=wrow[3],
                 w4=wrow[4], w5=wrow[5], w6=wrow[6], w7=wrow[7];
    float a0=0.f, a1=0.f, a2=0.f;
    for (int q=g; q<Kc; q+=8){
      const float* se = &sE[q*SES];
      float ev;
      ev  = w0.x*se[0]  + w0.y*se[1]  + w0.z*se[2]  + w0.w*se[3];
      ev += w1.x*se[4]  + w1.y*se[5]  + w1.z*se[6]  + w1.w*se[7];
      ev += w2.x*se[8]  + w2.y*se[9]  + w2.z*se[10] + w2.w*se[11];
      ev += w3.x*se[12] + w3.y*se[13] + w3.z*se[14] + w3.w*se[15];
      ev += w4.x*se[16] + w4.y*se[17] + w4.z*se[18] + w4.w*se[19];
      ev += w5.x*se[20] + w5.y*se[21] + w5.z*se[22] + w5.w*se[23];
      ev += w6.x*se[24] + w6.y*se[25] + w6.z*se[26] + w6.w*se[27];
      ev += w7.x*se[28] + w7.y*se[29] + w7.z*se[30] + w7.w*se[31];
      const float u = lrelu(ev + nb[(size_t)cdst[q]*EMB + o]);
      a0 += pp[0*CAP+q]*u;
      a1 += pp[1*CAP+q]*u;
      a2 += pp[2*CAP+q]*u;
    }
    // pre-combine pairs (g, g+1) within the wave: g even <-> lane<32
    a0 += __shfl_down(a0, 32, 64);
    a1 += __shfl_down(a1, 32, 64);
    a2 += __shfl_down(a2, 32, 64);
    if ((g & 1) == 0){
      const int gg = g >> 1;
      partial[gg*96 +      o] = a0;
      partial[gg*96 + 32 + o] = a1;
      partial[gg*96 + 64 + o] = a2;
    }
  }
  __syncthreads();                                      // barrier 5
  if (t < 96){
    float s = 0.f;
    #pragma unroll
    for (int g=0; g<4; g++) s += partial[g*96 + t];
    out[(size_t)r*96 + t] = s / hden[t>>5];
  }
}

extern "C" void kernel_launch(void* const* d_in, const int* in_sizes, int n_in,
                              void* d_out, int out_size, void* d_ws, size_t ws_size,
                              hipStream_t stream)
{
  (void)in_sizes; (void)n_in; (void)out_size; (void)ws_size;
  const float* node_f    = (const float*)d_in[0];
  const float* edge_attr = (const float*)d_in[1];
  const float* edge_type = (const float*)d_in[2];
  const float* W_veh     = (const float*)d_in[3];
  const float* W_ped     = (const float*)d_in[4];
  const float* W_ea      = (const float*)d_in[5];
  const float* W_et      = (const float*)d_in[6];
  const float* W_att     = (const float*)d_in[7];
  const float* W_upd     = (const float*)d_in[8];
  const int*   ei        = (const int*)d_in[9];
  const unsigned char* veh_mask = (const unsigned char*)d_in[10];
  float* out = (float*)d_out;

  char* ws = (char*)d_ws;
  const size_t oCnt  = 0;                              // REP*NN ints = 24 KB (zeroed in-kernel)
  const size_t oFlag = oCnt  + (size_t)REP*NN*4;       // 1 int ready-flag (poison != MAGIC each iteration)
  const size_t oSegF = oFlag + 16;                     // REP*NN*CAP2 float4 (24592 % 16 == 0)
  const size_t oSegD = oSegF + (size_t)REP*NN*CAP2*16;
  const size_t oTar  = oSegD + (size_t)REP*NN*CAP2*4;
  const size_t oNbr  = oTar  + (size_t)NN*4*4;
  const size_t oNb   = oNbr  + (size_t)NN*4*4;

  int*    cnt  = (int*)   (ws + oCnt);
  int*    flag = (int*)   (ws + oFlag);
  float4* segF = (float4*)(ws + oSegF);
  int*    segD = (int*)   (ws + oSegD);
  float*  tar  = (float*) (ws + oTar);
  float*  nbr  = (float*) (ws + oNbr);
  float*  nb   = (float*) (ws + oNb);

  // no memset dispatch: block 0 of k_prep zeroes counters and publishes the flag

  k_prep<<<1 + EBLK + NBLK, 256, 0, stream>>>(node_f, edge_attr, edge_type,
                                              W_veh, W_ped, W_att, W_upd,
                                              ei, veh_mask, cnt, flag, segD, segF,
                                              tar, nbr, nb);
  k_rows<<<NN, 256, 0, stream>>>(cnt, segD, segF, W_ea, W_et, W_att, W_upd,
                                 tar, nbr, nb, out);
}

// Round 9
// 114.411 us; speedup vs baseline: 1.0916x; 1.0916x over previous
//
#include <hip/hip_runtime.h>
#include <stdint.h>

#define NN 1536
#define EE 49152
#define EMB 32
#define HEADS 3
#define SLOPE 0.2f
#define CAP 72             // per-row total capacity; degree ~ Poisson(32), measured max ~60
#define REP 4              // counter/bucket replication
#define CAP2 28            // per-replica capacity; per-replica degree ~ Poisson(8), P(>28) ~ 1e-9
#define SES 67             // sE row stride (67 mod 32 = 3, coprime -> conflict-free strided reads)
#define EBLK (EE/256)      // 192 edge blocks
#define NBLK (NN/8)        // 192 node blocks

__device__ __forceinline__ float lrelu(float x){ return x >= 0.f ? x : SLOPE*x; }

// ---- runtime detection of bool-mask storage (int32 / uint8 / f32) ----
__device__ int detect_mask_layout(const unsigned char* p){
  const int* pi = (const int*)p;
  bool ok = true;
  for (int k=0;k<64 && ok;k++){ int v = pi[k]; ok = (v==0 || v==1); }
  if (ok) return 0;
  ok = true;
  for (int k=0;k<256 && ok;k++){ ok = (p[k] <= 1); }
  if (ok) return 1;
  return 2;
}
__device__ bool mask_at(const unsigned char* p, int layout, int i){
  if (layout==0) return ((const int*)p)[i] != 0;
  if (layout==1) return p[i] != 0;
  return ((const float*)p)[i] != 0.f;
}

// ---- K1: blocks [0,192): bucket insert, replica = block&3 (1 thread/edge).
//          blocks [192, 384): node embeddings. ----
__global__ __launch_bounds__(256) void k_prep(
    const float* __restrict__ node_f,
    const float* __restrict__ edge_attr, const float* __restrict__ edge_type,
    const float* __restrict__ W_veh, const float* __restrict__ W_ped,
    const float* __restrict__ W_att, const float* __restrict__ W_upd,
    const int* __restrict__ ei, const unsigned char* __restrict__ veh_mask,
    int* __restrict__ cnt, int* __restrict__ segD, float4* __restrict__ segF,
    float* __restrict__ tar, float* __restrict__ nbr, float* __restrict__ nb)
{
  const int t = threadIdx.x;
  const int b = blockIdx.x;

  if (b < EBLK){
    const int e = b*256 + t;
    const int j = b & (REP-1);
    const int s = ei[e], d = ei[EE + e];
    const float2 ea = ((const float2*)edge_attr)[e];
    const float2 et = ((const float2*)edge_type)[e];
    const int idx = atomicAdd(&cnt[j*NN + s], 1);
    if (idx < CAP2){
      const size_t sb = ((size_t)j*NN + s)*CAP2 + idx;
      segD[sb] = d;
      segF[sb] = make_float4(ea.x, ea.y, et.x, et.y);
    }
    return;
  }

  // -------- node path: 8 nodes/block, 32 threads/node --------
  __shared__ float sWvehT[EMB*33], sWpedT[EMB*33], sWunT[EMB*33];
  __shared__ float sWt[HEADS*EMB], sWn[HEADS*EMB];
  __shared__ float sF[8*EMB], sEmb[8*EMB];
  __shared__ int layout_s;
  const int i0 = (b - EBLK)*8;
  if (t == 0) layout_s = detect_mask_layout(veh_mask);
  for (int idx=t; idx<EMB*EMB; idx+=256){
    const int mm = idx>>5, kk = idx&31;
    sWvehT[mm*33+kk] = W_veh[idx];
    sWpedT[mm*33+kk] = W_ped[idx];
    sWunT[mm*33+kk]  = W_upd[mm*64 + EMB + kk];   // Wu_n = W_upd[:,32:]
  }
  if (t < HEADS*EMB){
    const int h = t>>5, c = t&31;
    sWt[t] = W_att[h*128 + c];        // W_tar
    sWn[t] = W_att[h*128 + 96 + c];   // W_nbr
  }
  sF[t] = node_f[(size_t)i0*EMB + t];
  __syncthreads();

  const int li = t >> 5, m = t & 31;
  const int i = i0 + li;
  const bool veh = mask_at(veh_mask, layout_s, i);
  const float* WT = veh ? sWvehT : sWpedT;
  float a = 0.f;
  #pragma unroll
  for (int k=0;k<EMB;k++) a += sF[li*EMB+k] * WT[m*33+k];
  sEmb[li*EMB+m] = lrelu(a);
  __syncthreads();

  float bb = 0.f;
  #pragma unroll
  for (int k=0;k<EMB;k++) bb += sEmb[li*EMB+k] * sWunT[m*33+k];
  nb[(size_t)i*EMB + m] = bb;
  if (m < 3){
    float v = 0.f;
    #pragma unroll
    for (int k=0;k<EMB;k++) v += sEmb[li*EMB+k] * sWt[m*EMB+k];
    tar[i*4+m] = v;
  } else if (m < 6){
    const int h = m-3;
    float v = 0.f;
    #pragma unroll
    for (int k=0;k<EMB;k++) v += sEmb[li*EMB+k] * sWn[h*EMB+k];
    nbr[i*4+h] = v;
  }
}

// ---- K2: one block per src row; concatenates the 4 replica sub-buckets.
//          25.6 KB LDS -> 6 blocks/CU -> all 1536 rows resident, one pass. ----
__global__ __launch_bounds__(256, 6) void k_rows(
    const int* __restrict__ cnt, const int* __restrict__ segD,
    const float4* __restrict__ segF,
    const float* __restrict__ W_ea, const float* __restrict__ W_et,
    const float* __restrict__ W_att, const float* __restrict__ W_upd,
    const float* __restrict__ tar, const float* __restrict__ nbr,
    const float* __restrict__ nb, float* __restrict__ out)
{
  const int r = blockIdx.x;
  const int t = threadIdx.x;

  __shared__ int   ld[CAP], canon[CAP], slotidx[CAP], slotof[CAP], cdst[CAP];
  __shared__ float4 pay[CAP];
  __shared__ float sE[CAP*SES];          // per-slot [emb_ea(32) | pad | emb_et(32) | pad2]
  __shared__ float sWea[64], sWet[64], sWedge[HEADS*64];
  __shared__ float pp[HEADS*CAP];
  __shared__ float partial[4*96];
  __shared__ float hden[HEADS];
  __shared__ int np_s, hasdup_s;

  if (t < 64){ sWea[t] = W_ea[t]; sWet[t] = W_et[t]; }
  if (t < HEADS*64) sWedge[t] = W_att[(t>>6)*128 + EMB + (t&63)];   // W_edge
  if (t == 0){ np_s = 0; hasdup_s = 0; }

  // replica counts (uniform scalar loads)
  const int k0 = min(cnt[0*NN + r], CAP2);
  const int k1 = min(cnt[1*NN + r], CAP2);
  const int k2 = min(cnt[2*NN + r], CAP2);
  const int k3 = min(cnt[3*NN + r], CAP2);
  const int o1 = k0, o2 = k0+k1, o3 = k0+k1+k2;
  const int K = min(o3 + k3, CAP);

  if (K == 0){
    // all scores -10000 -> uniform attention over all nodes (lazy fallback; ~never taken)
    float* fb = pp;
    if (t < EMB) fb[t] = 0.f;
    __syncthreads();
    for (int idx=t; idx<NN*EMB; idx+=256) atomicAdd(&fb[idx&31], lrelu(nb[idx]));
    __syncthreads();
    if (t < 96) out[(size_t)r*96 + t] = fb[t&31] * (1.0f/NN);
    return;
  }

  for (int i=t; i<K; i+=256){
    int j, ii;
    if (i < o1){ j = 0; ii = i; }
    else if (i < o2){ j = 1; ii = i - o1; }
    else if (i < o3){ j = 2; ii = i - o2; }
    else { j = 3; ii = i - o3; }
    const size_t sb = ((size_t)j*NN + r)*CAP2 + ii;
    const int d = segD[sb];
    ld[i]  = d;
    cdst[i] = d;                // speculative (valid if no dups)
    pay[i] = segF[sb];
    canon[i] = i;
  }
  __syncthreads();                                      // barrier 1

  // dedup sweep: atomicMin canon + dup flag in one pass
  for (int p=t; p<K*K; p+=256){
    const int i = p / K, j = p - i*K;
    if (j < i && ld[i] == ld[j]){ atomicMin(&canon[i], j); hasdup_s = 1; }
  }
  __syncthreads();                                      // barrier 2

  const bool dup = (hasdup_s != 0);                     // block-uniform
  int Kc = K;
  if (dup){
    // rare path (~28% of rows): compact slots + merge payload sums
    for (int i=t; i<K; i+=256){
      if (canon[i] == i){
        const int s2 = atomicAdd(&np_s, 1);
        slotidx[i] = s2;
        cdst[s2]   = ld[i];
      }
    }
    __syncthreads();
    Kc = np_s;
    for (int i=t; i<K; i+=256) slotof[i] = slotidx[canon[i]];
    for (int idx=t; idx<Kc*SES; idx+=256) sE[idx] = 0.f;
    __syncthreads();
  }

  // per-entry 64-dim edge embedding -> per-slot (sum); linear downstream so summing embs == summing eau/se
  for (int idx=t; idx<K*EMB; idx+=256){
    const int q = idx>>5, m = idx&31;
    const float4 p4 = pay[q];
    const float ea_ = lrelu(p4.x*sWea[2*m] + p4.y*sWea[2*m+1]);
    const float et_ = lrelu(p4.z*sWet[2*m] + p4.w*sWet[2*m+1]);
    if (!dup){
      sE[q*SES + m]      = ea_;
      sE[q*SES + 33 + m] = et_;
    } else {
      const int sl = slotof[q];
      atomicAdd(&sE[sl*SES + m],      ea_);
      atomicAdd(&sE[sl*SES + 33 + m], et_);
    }
  }
  __syncthreads();                                      // barrier 3

  // softmax: head h = wave h; lane q; shfl reductions
  if (t < 192){
    const int h = t >> 6, lane = t & 63;
    const float th = tar[r*4+h];
    float mx = -1e30f;
    for (int q0=0; q0<Kc; q0+=64){
      const int q = q0 + lane;
      if (q < Kc){
        float sev = 0.f;
        #pragma unroll
        for (int k=0;k<EMB;k++)
          sev += sWedge[h*64+k]*sE[q*SES+k] + sWedge[h*64+EMB+k]*sE[q*SES+33+k];
        const float s = lrelu(th + sev + nbr[cdst[q]*4+h]);
        pp[h*CAP+q] = s;
        mx = fmaxf(mx, s);
      }
    }
    #pragma unroll
    for (int d=32; d; d>>=1) mx = fmaxf(mx, __shfl_xor(mx, d, 64));
    float den = 0.f;
    for (int q0=0; q0<Kc; q0+=64){
      const int q = q0 + lane;
      if (q < Kc){
        const float p = __expf(pp[h*CAP+q] - mx);
        pp[h*CAP+q] = p;
        den += p;
      }
    }
    #pragma unroll
    for (int d=32; d; d>>=1) den += __shfl_xor(den, d, 64);
    if (lane == 0) hden[h] = den;
  }
  __syncthreads();                                      // barrier 4

  // output: 8 q-groups x 32 o-lanes; Wu_e row o streamed from global into regs (phase-local)
  {
    const int g = t >> 5, o = t & 31;
    const float4* wrow = (const float4*)(W_upd + (size_t)o*64);  // Wu_e row o = W_upd[o*64 + 0..31]
    const float4 w0=wrow[0], w1=wrow[1], w2=wrow[2], w3=wrow[3],
                 w4=wrow[4], w5=wrow[5], w6=wrow[6], w7=wrow[7];
    float a0=0.f, a1=0.f, a2=0.f;
    for (int q=g; q<Kc; q+=8){
      const float* se = &sE[q*SES];
      float ev;
      ev  = w0.x*se[0]  + w0.y*se[1]  + w0.z*se[2]  + w0.w*se[3];
      ev += w1.x*se[4]  + w1.y*se[5]  + w1.z*se[6]  + w1.w*se[7];
      ev += w2.x*se[8]  + w2.y*se[9]  + w2.z*se[10] + w2.w*se[11];
      ev += w3.x*se[12] + w3.y*se[13] + w3.z*se[14] + w3.w*se[15];
      ev += w4.x*se[16] + w4.y*se[17] + w4.z*se[18] + w4.w*se[19];
      ev += w5.x*se[20] + w5.y*se[21] + w5.z*se[22] + w5.w*se[23];
      ev += w6.x*se[24] + w6.y*se[25] + w6.z*se[26] + w6.w*se[27];
      ev += w7.x*se[28] + w7.y*se[29] + w7.z*se[30] + w7.w*se[31];
      const float u = lrelu(ev + nb[(size_t)cdst[q]*EMB + o]);
      a0 += pp[0*CAP+q]*u;
      a1 += pp[1*CAP+q]*u;
      a2 += pp[2*CAP+q]*u;
    }
    // pre-combine pairs (g, g+1) within the wave: g even <-> lane<32
    a0 += __shfl_down(a0, 32, 64);
    a1 += __shfl_down(a1, 32, 64);
    a2 += __shfl_down(a2, 32, 64);
    if ((g & 1) == 0){
      const int gg = g >> 1;
      partial[gg*96 +      o] = a0;
      partial[gg*96 + 32 + o] = a1;
      partial[gg*96 + 64 + o] = a2;
    }
  }
  __syncthreads();                                      // barrier 5
  if (t < 96){
    float s = 0.f;
    #pragma unroll
    for (int g=0; g<4; g++) s += partial[g*96 + t];
    out[(size_t)r*96 + t] = s / hden[t>>5];
  }
}

extern "C" void kernel_launch(void* const* d_in, const int* in_sizes, int n_in,
                              void* d_out, int out_size, void* d_ws, size_t ws_size,
                              hipStream_t stream)
{
  (void)in_sizes; (void)n_in; (void)out_size; (void)ws_size;
  const float* node_f    = (const float*)d_in[0];
  const float* edge_attr = (const float*)d_in[1];
  const float* edge_type = (const float*)d_in[2];
  const float* W_veh     = (const float*)d_in[3];
  const float* W_ped     = (const float*)d_in[4];
  const float* W_ea      = (const float*)d_in[5];
  const float* W_et      = (const float*)d_in[6];
  const float* W_att     = (const float*)d_in[7];
  const float* W_upd     = (const float*)d_in[8];
  const int*   ei        = (const int*)d_in[9];
  const unsigned char* veh_mask = (const unsigned char*)d_in[10];
  float* out = (float*)d_out;

  char* ws = (char*)d_ws;
  const size_t cntBytes = (size_t)REP*NN*4;           // 24 KB of counters
  const size_t oCnt  = 0;
  const size_t oSegF = oCnt  + cntBytes;              // REP*NN*CAP2 float4 (24576 % 16 == 0)
  const size_t oSegD = oSegF + (size_t)REP*NN*CAP2*16;
  const size_t oTar  = oSegD + (size_t)REP*NN*CAP2*4;
  const size_t oNbr  = oTar  + (size_t)NN*4*4;
  const size_t oNb   = oNbr  + (size_t)NN*4*4;

  int*    cnt  = (int*)   (ws + oCnt);
  float4* segF = (float4*)(ws + oSegF);
  int*    segD = (int*)   (ws + oSegD);
  float*  tar  = (float*) (ws + oTar);
  float*  nbr  = (float*) (ws + oNbr);
  float*  nb   = (float*) (ws + oNb);

  hipMemsetAsync(ws + oCnt, 0, cntBytes, stream);   // counters = 0 (24 KB)

  k_prep<<<EBLK + NBLK, 256, 0, stream>>>(node_f, edge_attr, edge_type,
                                          W_veh, W_ped, W_att, W_upd,
                                          ei, veh_mask, cnt, segD, segF,
                                          tar, nbr, nb);
  k_rows<<<NN, 256, 0, stream>>>(cnt, segD, segF, W_ea, W_et, W_att, W_upd,
                                 tar, nbr, nb, out);
}